// Round 1
// baseline (364.395 us; speedup 1.0000x reference)
//
#include <hip/hip_runtime.h>
#include <hip/hip_bf16.h>

#define Bq 2
#define Lq 384
#define Cq 128
#define Hq 8

static constexpr float WCH   = 0.11785113019775792f;  // sqrt(2/36)/2
static constexpr float WLc   = 0.5773502691896258f;   // sqrt(1/3)
static constexpr float LOG2E = 1.4426950408889634f;

typedef __attribute__((ext_vector_type(8))) short bf16x8;
typedef __attribute__((ext_vector_type(4))) float f32x4;

__device__ __forceinline__ unsigned short f2bf(float f) {
  __hip_bfloat16 h = __float2bfloat16(f);
  unsigned short u; __builtin_memcpy(&u, &h, 2); return u;
}
__device__ __forceinline__ unsigned packbf(float a, float b) {
  return (unsigned)f2bf(a) | ((unsigned)f2bf(b) << 16);
}
__device__ __forceinline__ float bf2f(unsigned short u) {
  unsigned x = ((unsigned)u) << 16; float f; __builtin_memcpy(&f, &x, 4); return f;
}
__device__ __forceinline__ bf16x8 ld_frag(const unsigned* p) {
  union { bf16x8 v; unsigned u[4]; } x;
  x.u[0] = p[0]; x.u[1] = p[1]; x.u[2] = p[2]; x.u[3] = p[3];
  return x.v;
}

// ---------------- kernel 1a: all si projections via MFMA --------------------
// A = si (64 tok x 128c), B tiles of 128 cols from the 6 weight mats.
// scalar cols (q,k,v) -> ws f32 directly; point cols -> raw[tok][384].
__global__ __launch_bounds__(256) void k_proj(
    const float* __restrict__ si,
    const float* __restrict__ WQh, const float* __restrict__ WKh, const float* __restrict__ WVh,
    const float* __restrict__ WQhp, const float* __restrict__ WKhp, const float* __restrict__ WVhp,
    float* __restrict__ q, float* __restrict__ k, float* __restrict__ v,
    float* __restrict__ raw)
{
  __shared__ unsigned sm[4288 + 8576];
  unsigned* at = sm;           // 64 rows x 67 dw (134 bf16, stride keeps banks spread)
  unsigned* bt = sm + 4288;    // 128 rows x 67 dw, stored [col][c]
  unsigned short* at16 = (unsigned short*)at;
  unsigned short* bt16 = (unsigned short*)bt;
  const int t = threadIdx.x;
  const int tb = blockIdx.x >> 1, nh = blockIdx.x & 1;
  const int tok0 = tb * 64;

  for (int rep = 0; rep < 32; ++rep) {
    int idx = rep*256 + t;            // 64*128
    int tl = idx >> 7, c = idx & 127;
    at16[tl*134 + c] = f2bf(si[(tok0+tl)*128 + c]);
  }
  __syncthreads();
  const int l = t & 63, w = t >> 6, g = l >> 4, n16 = l & 15;
  bf16x8 afr[4];
  #pragma unroll
  for (int ks = 0; ks < 4; ++ks)
    afr[ks] = ld_frag(&at[(w*16 + n16)*67 + ks*16 + g*4]);

  for (int nt3 = 0; nt3 < 3; ++nt3) {
    int nt = nh*3 + nt3;
    __syncthreads();
    for (int rep = 0; rep < 64; ++rep) {
      int idx = rep*256 + t;          // 128*128
      int c = idx >> 7, col = idx & 127;
      float wv;
      if (nt < 3) {
        const float* W = (nt == 0) ? WQh : (nt == 1) ? WKh : WVh;
        wv = W[c*128 + col];
      } else {
        int pc = (nt-3)*128 + col;
        if (pc < 96)       wv = WQhp[c*96 + pc];
        else if (pc < 192) wv = WKhp[c*96 + (pc-96)];
        else               wv = WVhp[c*192 + (pc-192)];
      }
      bt16[col*134 + c] = f2bf(wv);
    }
    __syncthreads();
    for (int ns = 0; ns < 8; ++ns) {
      f32x4 acc = {0.f,0.f,0.f,0.f};
      #pragma unroll
      for (int ks = 0; ks < 4; ++ks) {
        bf16x8 bfr = ld_frag(&bt[(ns*16 + n16)*67 + ks*16 + g*4]);
        acc = __builtin_amdgcn_mfma_f32_16x16x32_bf16(afr[ks], bfr, acc, 0, 0, 0);
      }
      #pragma unroll
      for (int r = 0; r < 4; ++r) {
        int tok = tok0 + w*16 + g*4 + r;
        int col = ns*16 + n16;
        if (nt < 3) {
          float* dst = (nt==0) ? q : (nt==1) ? k : v;
          dst[tok*128 + col] = acc[r];
        } else {
          raw[tok*384 + (nt-3)*128 + col] = acc[r];
        }
      }
    }
  }
}

// ---------------- kernel 1b: rigid transforms + |pt|^2 sums -----------------
__global__ __launch_bounds__(256) void k_xform(
    const float* __restrict__ raw, const float* __restrict__ Ri, const float* __restrict__ Ti,
    float* __restrict__ qpt, float* __restrict__ kpt, float* __restrict__ vpt,
    float* __restrict__ sqq, float* __restrict__ sqk)
{
  __shared__ float ssq[128];
  const int t = threadIdx.x;
  const int tk = t >> 7, pt = t & 127;
  const int tok = blockIdx.x*2 + tk;
  const float* R = Ri + tok*9;
  const float* T = Ti + tok*3;
  int ro = (pt < 32) ? pt*3 : (pt < 64) ? 96 + (pt-32)*3 : 192 + (pt-64)*3;
  float x0 = raw[tok*384 + ro + 0], x1 = raw[tok*384 + ro + 1], x2 = raw[tok*384 + ro + 2];
  float o0 = T[0] + R[0]*x0 + R[1]*x1 + R[2]*x2;
  float o1 = T[1] + R[3]*x0 + R[4]*x1 + R[5]*x2;
  float o2 = T[2] + R[6]*x0 + R[7]*x1 + R[8]*x2;
  float* dst; int doff;
  if (pt < 32)      { dst = qpt; doff = tok*96  + pt*3; }
  else if (pt < 64) { dst = kpt; doff = tok*96  + (pt-32)*3; }
  else              { dst = vpt; doff = tok*192 + (pt-64)*3; }
  dst[doff] = o0; dst[doff+1] = o1; dst[doff+2] = o2;
  if (pt < 64) ssq[tk*64 + pt] = o0*o0 + o1*o1 + o2*o2;
  __syncthreads();
  if (t < 32) {
    int tk2 = t >> 4, r = t & 15, isK = r >> 3, h = r & 7;
    int base = tk2*64 + isK*32 + h*4;
    float s = ssq[base] + ssq[base+1] + ssq[base+2] + ssq[base+3];
    int tok2 = blockIdx.x*2 + tk2;
    (isK ? sqk : sqq)[tok2*8 + h] = s;
  }
}

// ---------------- kernel geom: g[b,h,i,j] (all non-zij score terms) ---------
// K=32 concat: [q*WL/4 | qpt*c2 | -c3*sqq | -c3]  vs  [k | kpt | 1 | sqk]
__global__ __launch_bounds__(256) void k_geom(
    const float* __restrict__ q, const float* __restrict__ k,
    const float* __restrict__ qpt, const float* __restrict__ kpt,
    const float* __restrict__ sqq, const float* __restrict__ sqk,
    const float* __restrict__ gamah, float* __restrict__ g)
{
  __shared__ unsigned sm[1152 + 6912];
  unsigned* at = sm;          // 64 x 18 dw (36 bf16)
  unsigned* bt = sm + 1152;   // 384 x 18 dw
  unsigned short* at16 = (unsigned short*)at;
  unsigned short* bt16 = (unsigned short*)bt;
  const int t = threadIdx.x;
  const int bh = blockIdx.x / 6, ib = blockIdx.x % 6;
  const int b = bh >> 3, h = bh & 7, i0 = ib*64;
  float gv = gamah[h];
  float sp = (gv > 20.f) ? gv : log1pf(__expf(gv));
  float c1 = WLc*0.25f, c2 = 2.f*WLc*sp*WCH, c3 = WLc*sp*WCH;

  for (int rep = 0; rep < 8; ++rep) {
    int idx = rep*256 + t;            // 64*32
    int il = idx >> 5, kk = idx & 31;
    int tok = b*Lq + i0 + il;
    float val;
    if (kk < 16)       val = q  [tok*128 + h*16 + kk] * c1;
    else if (kk < 28)  val = qpt[tok*96  + h*12 + kk-16] * c2;
    else if (kk == 28) val = -c3 * sqq[tok*8 + h];
    else if (kk == 29) val = -c3;
    else               val = 0.f;
    at16[il*36 + kk] = f2bf(val);
  }
  for (int rep = 0; rep < 48; ++rep) {
    int idx = rep*256 + t;            // 384*32
    int jl = idx >> 5, kk = idx & 31;
    int tok = b*Lq + jl;
    float val;
    if (kk < 16)       val = k  [tok*128 + h*16 + kk];
    else if (kk < 28)  val = kpt[tok*96  + h*12 + kk-16];
    else if (kk == 28) val = 1.f;
    else if (kk == 29) val = sqk[tok*8 + h];
    else               val = 0.f;
    bt16[jl*36 + kk] = f2bf(val);
  }
  __syncthreads();
  const int l = t & 63, w = t >> 6, g2 = l >> 4, n16 = l & 15;
  bf16x8 afr = ld_frag(&at[(w*16 + n16)*18 + g2*4]);
  float* grow = g + (size_t)(b*8 + h)*Lq*Lq;
  for (int jt = 0; jt < 24; ++jt) {
    bf16x8 bfr = ld_frag(&bt[(jt*16 + n16)*18 + g2*4]);
    f32x4 acc = {0.f,0.f,0.f,0.f};
    acc = __builtin_amdgcn_mfma_f32_16x16x32_bf16(afr, bfr, acc, 0, 0, 0);
    #pragma unroll
    for (int r = 0; r < 4; ++r) {
      int irow = i0 + w*16 + g2*4 + r;
      grow[(size_t)irow*Lq + jt*16 + n16] = acc[r];
    }
  }
}

// ---------------- kernel attn: flash-style row attention over zij -----------
// LDS dword offsets
#define ZS   0        // z row-major   64 x 67dw (134 bf16)
#define ZT   4288     // z transposed 128 x 35dw (70 bf16)
#define GS   8768     // g rows        8 x 387dw f32
#define P2O  11864    // P bf16       16 x 35dw
#define WBT  12424    // Wb^T bf16    16 x 67dw (rows 8..15 zero)
#define WMX  13496    // 4x16 f32
#define LSM  13560    // 4x16 f32
#define SCL  13624    // 8 f32
#define INV  13632    // 8 f32
#define OPTS 13640    // 192 f32
#define OS   13832    // 1024 f32
#define SMTOT 14856

__global__ __launch_bounds__(256, 2) void k_attn(
    const float* __restrict__ zij, const float* __restrict__ gmat,
    const float* __restrict__ v, const float* __restrict__ vpt,
    const float* __restrict__ Wb, const float* __restrict__ Ri, const float* __restrict__ Ti,
    float* __restrict__ feats)
{
  __shared__ unsigned sm[SMTOT];
  float* smf = (float*)sm;
  unsigned short* zs16 = (unsigned short*)(sm + ZS);
  const int t = threadIdx.x;
  const int bx = blockIdx.x;
  const int b = bx / Lq, i = bx % Lq;
  const int tok = bx;
  const int l = t & 63, w = t >> 6, g = l >> 4, hh = l & 15;

  {
    const float* gp = gmat + (size_t)(b*8)*Lq*Lq + (size_t)i*Lq;
    for (int rep = 0; rep < 12; ++rep) {
      int idx = rep*256 + t;          // 8*384
      int h2 = idx / 384, j = idx % 384;
      smf[GS + h2*387 + j] = gp[(size_t)h2*Lq*Lq + j];
    }
    unsigned short* wb16 = (unsigned short*)(sm + WBT);
    for (int rep = 0; rep < 8; ++rep) {
      int idx = rep*256 + t;          // 16*128
      int h2 = idx >> 7, c = idx & 127;
      wb16[h2*134 + c] = (h2 < 8) ? f2bf(Wb[c*8 + h2]) : (unsigned short)0;
    }
  }
  __syncthreads();
  bf16x8 wbf[4];
  #pragma unroll
  for (int ks = 0; ks < 4; ++ks) wbf[ks] = ld_frag(&sm[WBT + hh*67 + ks*16 + g*4]);

  f32x4 opacc0 = {0.f,0.f,0.f,0.f}, opacc1 = {0.f,0.f,0.f,0.f};
  float m_run = -1e30f, l_run = 0.f;
  float va0 = 0.f, va1 = 0.f;
  int role_h = 0; const float* rp = nullptr; int rstride = 0;
  if (t < 64)       { role_h = t >> 3; rp = v   + (size_t)b*Lq*128 + role_h*16 + (t & 7)*2; rstride = 128; }
  else if (t < 160) { int qq = t - 64; role_h = qq / 12;
                      rp = vpt + (size_t)b*Lq*192 + role_h*24 + (qq % 12)*2; rstride = 192; }
  const size_t zbase = (size_t)(b*Lq + i)*Lq*128;
  const int cS = t & 127, jqS = t >> 7;

  for (int ch = 0; ch < 6; ++ch) {
    const int j0 = ch*64;
    __syncthreads();                                   // B0: prior reads of z/P done
    #pragma unroll
    for (int pp = 0; pp < 8; ++pp) {
      int jb = pp*8 + jqS*4;
      float z0 = zij[zbase + (size_t)(j0+jb+0)*128 + cS];
      float z1 = zij[zbase + (size_t)(j0+jb+1)*128 + cS];
      float z2 = zij[zbase + (size_t)(j0+jb+2)*128 + cS];
      float z3 = zij[zbase + (size_t)(j0+jb+3)*128 + cS];
      sm[ZT + cS*35 + (jb>>1)    ] = packbf(z0, z1);
      sm[ZT + cS*35 + (jb>>1) + 1] = packbf(z2, z3);
      zs16[(jb+0)*134 + cS] = f2bf(z0);
      zs16[(jb+1)*134 + cS] = f2bf(z1);
      zs16[(jb+2)*134 + cS] = f2bf(z2);
      zs16[(jb+3)*134 + cS] = f2bf(z3);
    }
    __syncthreads();                                   // B1: z staged
    // bij for this wave's 16-j tile (jt = w)
    f32x4 bij = {0.f,0.f,0.f,0.f};
    #pragma unroll
    for (int ks = 0; ks < 4; ++ks) {
      bf16x8 a = ld_frag(&sm[ZS + (w*16 + hh)*67 + ks*16 + g*4]);
      bij = __builtin_amdgcn_mfma_f32_16x16x32_bf16(a, wbf[ks], bij, 0, 0, 0);
    }
    float s0, s1, s2, s3;
    if (hh < 8) {
      const float* gr = &smf[GS + hh*387 + j0 + w*16 + g*4];
      s0 = gr[0] + WLc*bij[0]; s1 = gr[1] + WLc*bij[1];
      s2 = gr[2] + WLc*bij[2]; s3 = gr[3] + WLc*bij[3];
    } else { s0 = s1 = s2 = s3 = -1e30f; }
    float m4 = fmaxf(fmaxf(s0,s1), fmaxf(s2,s3));
    m4 = fmaxf(m4, __shfl_xor(m4, 16));
    m4 = fmaxf(m4, __shfl_xor(m4, 32));
    if (l < 16) smf[WMX + w*16 + l] = m4;
    __syncthreads();                                   // B2: wave maxes ready
    float cmax = fmaxf(fmaxf(smf[WMX+hh], smf[WMX+16+hh]),
                       fmaxf(smf[WMX+32+hh], smf[WMX+48+hh]));
    float m_new = fmaxf(m_run, cmax);
    float sc = exp2f((m_run - m_new)*LOG2E);
    m_run = m_new;
    float p0 = exp2f((s0 - m_new)*LOG2E);
    float p1 = exp2f((s1 - m_new)*LOG2E);
    float p2 = exp2f((s2 - m_new)*LOG2E);
    float p3 = exp2f((s3 - m_new)*LOG2E);
    float psum = p0+p1+p2+p3;
    psum += __shfl_xor(psum, 16);
    psum += __shfl_xor(psum, 32);
    l_run = l_run*sc + psum;
    sm[P2O + hh*35 + w*8 + g*2    ] = packbf(p0, p1);
    sm[P2O + hh*35 + w*8 + g*2 + 1] = packbf(p2, p3);
    opacc0 = opacc0 * sc;
    opacc1 = opacc1 * sc;
    if (w == 0 && l < 8) smf[SCL + l] = sc;
    __syncthreads();                                   // B3: P + scale ready
    #pragma unroll
    for (int ks = 0; ks < 2; ++ks) {
      bf16x8 bb = ld_frag(&sm[P2O + hh*35 + ks*16 + g*4]);
      bf16x8 a0 = ld_frag(&sm[ZT + ((w  )*16 + hh)*35 + ks*16 + g*4]);
      bf16x8 a1 = ld_frag(&sm[ZT + ((w+4)*16 + hh)*35 + ks*16 + g*4]);
      opacc0 = __builtin_amdgcn_mfma_f32_16x16x32_bf16(a0, bb, opacc0, 0, 0, 0);
      opacc1 = __builtin_amdgcn_mfma_f32_16x16x32_bf16(a1, bb, opacc1, 0, 0, 0);
    }
    if (t < 160) {
      float scl = smf[SCL + role_h];
      va0 *= scl; va1 *= scl;
      #pragma unroll 4
      for (int jj = 0; jj < 64; jj += 2) {
        unsigned pw = sm[P2O + role_h*35 + (jj>>1)];
        float pa = bf2f((unsigned short)(pw & 0xffffu));
        float pb = bf2f((unsigned short)(pw >> 16));
        const float* pj = rp + (size_t)(j0+jj)*rstride;
        const float* pk2 = pj + rstride;
        va0 += pa*pj[0] + pb*pk2[0];
        va1 += pa*pj[1] + pb*pk2[1];
      }
    }
  }
  __syncthreads();
  if (l < 16) smf[LSM + w*16 + l] = l_run;
  __syncthreads();
  if (t < 8) {
    float lt = smf[LSM+t] + smf[LSM+16+t] + smf[LSM+32+t] + smf[LSM+48+t];
    smf[INV + t] = 1.f / lt;
  }
  __syncthreads();
  const size_t fb = (size_t)tok * 1408;
  if (hh < 8) {
    float inv = smf[INV + hh];
    #pragma unroll
    for (int r = 0; r < 4; ++r) {
      smf[OS + hh*128 + (w  )*16 + g*4 + r] = opacc0[r]*inv;
      smf[OS + hh*128 + (w+4)*16 + g*4 + r] = opacc1[r]*inv;
    }
  }
  if (t < 64) {
    float inv = smf[INV + role_h];
    int off = role_h*16 + (t & 7)*2;
    feats[fb + 1024 + off    ] = va0*inv;
    feats[fb + 1024 + off + 1] = va1*inv;
  } else if (t < 160) {
    float inv = smf[INV + role_h];
    int qq = t - 64;
    smf[OPTS + role_h*24 + (qq%12)*2    ] = va0*inv;
    smf[OPTS + role_h*24 + (qq%12)*2 + 1] = va1*inv;
  }
  __syncthreads();
  for (int rep = 0; rep < 4; ++rep) {
    int idx = rep*256 + t;
    feats[fb + idx] = smf[OS + idx];
  }
  if (t < 64) {
    int h2 = t >> 3, p = t & 7;
    const float* R = Ri + tok*9;
    const float* T = Ti + tok*3;
    float ox = smf[OPTS + h2*24 + p*3 + 0] - T[0];
    float oy = smf[OPTS + h2*24 + p*3 + 1] - T[1];
    float oz = smf[OPTS + h2*24 + p*3 + 2] - T[2];
    float r0 = R[0]*ox + R[3]*oy + R[6]*oz;
    float r1 = R[1]*ox + R[4]*oy + R[7]*oz;
    float r2 = R[2]*ox + R[5]*oy + R[8]*oz;
    feats[fb + 1152 + (h2*8+p)*3 + 0] = r0;
    feats[fb + 1152 + (h2*8+p)*3 + 1] = r1;
    feats[fb + 1152 + (h2*8+p)*3 + 2] = r2;
    feats[fb + 1344 + h2*8 + p] = fabsf(r0) + fabsf(r1) + fabsf(r2);
  }
}

// ---------------- kernel out: feats @ WOw + WOb (fp32, split-K) -------------
__global__ __launch_bounds__(256) void k_out(
    const float* __restrict__ feats, const float* __restrict__ WOw,
    const float* __restrict__ WOb, float* __restrict__ out)
{
  __shared__ float sf[8448];
  const int t = threadIdx.x;
  const int r0 = blockIdx.x * 6;
  for (int rep = 0; rep < 33; ++rep) {
    int idx = rep*256 + t;            // 6*1408
    int row = idx / 1408, f = idx % 1408;
    sf[f*6 + row] = feats[(size_t)(r0+row)*1408 + f];
  }
  __syncthreads();
  const int c4 = t & 31, fq = t >> 5;
  float acc[6][4];
  #pragma unroll
  for (int r = 0; r < 6; ++r)
    #pragma unroll
    for (int e = 0; e < 4; ++e) acc[r][e] = 0.f;
  const float* wp = WOw + (size_t)fq*176*128 + c4*4;
  for (int f = 0; f < 176; ++f) {
    const f32x4 wv = *(const f32x4*)(wp + (size_t)f*128);
    int fg = fq*176 + f;
    float fv[6];
    #pragma unroll
    for (int r = 0; r < 6; ++r) fv[r] = sf[fg*6 + r];
    #pragma unroll
    for (int r = 0; r < 6; ++r)
      #pragma unroll
      for (int e = 0; e < 4; ++e) acc[r][e] += fv[r]*wv[e];
  }
  __syncthreads();
  #pragma unroll
  for (int r = 0; r < 6; ++r)
    #pragma unroll
    for (int e = 0; e < 4; ++e)
      sf[(fq*6 + r)*128 + c4*4 + e] = acc[r][e];
  __syncthreads();
  for (int rep = 0; rep < 3; ++rep) {
    int idx = rep*256 + t;            // 768
    int r = idx >> 7, cc = idx & 127;
    float s = 0.f;
    #pragma unroll
    for (int fq2 = 0; fq2 < 8; ++fq2) s += sf[(fq2*6 + r)*128 + cc];
    out[(size_t)(r0+r)*128 + cc] = s + WOb[cc];
  }
}

// ---------------------------------------------------------------------------
extern "C" void kernel_launch(void* const* d_in, const int* in_sizes, int n_in,
                              void* d_out, int out_size, void* d_ws, size_t ws_size,
                              hipStream_t stream) {
  const float* si    = (const float*)d_in[0];
  const float* zij   = (const float*)d_in[1];
  const float* Ri    = (const float*)d_in[2];
  const float* Ti    = (const float*)d_in[3];
  const float* WQh   = (const float*)d_in[4];
  const float* WKh   = (const float*)d_in[5];
  const float* WVh   = (const float*)d_in[6];
  const float* WQhp  = (const float*)d_in[7];
  const float* WKhp  = (const float*)d_in[8];
  const float* WVhp  = (const float*)d_in[9];
  const float* Wb    = (const float*)d_in[10];
  const float* WOw   = (const float*)d_in[11];
  const float* WOb   = (const float*)d_in[12];
  const float* gamah = (const float*)d_in[13];

  float* ws   = (float*)d_ws;
  float* q    = ws;              // 768*128
  float* k    = q    + 98304;
  float* v    = k    + 98304;
  float* qpt  = v    + 98304;    // 768*96
  float* kpt  = qpt  + 73728;
  float* vpt  = kpt  + 73728;    // 768*192
  float* sqq  = vpt  + 147456;   // 768*8
  float* sqk  = sqq  + 6144;
  float* raw  = sqk  + 6144;     // 768*384
  float* g    = raw  + 294912;   // 2*8*384*384
  float* feats= g    + 2359296;  // 768*1408
  float* out  = (float*)d_out;

  k_proj <<<24,  256, 0, stream>>>(si, WQh, WKh, WVh, WQhp, WKhp, WVhp, q, k, v, raw);
  k_xform<<<384, 256, 0, stream>>>(raw, Ri, Ti, qpt, kpt, vpt, sqq, sqk);
  k_geom <<<96,  256, 0, stream>>>(q, k, qpt, kpt, sqq, sqk, gamah, g);
  k_attn <<<768, 256, 0, stream>>>(zij, g, v, vpt, Wb, Ri, Ti, feats);
  k_out  <<<128, 256, 0, stream>>>(feats, WOw, WOb, out);
}

// Round 3
// 314.415 us; speedup vs baseline: 1.1590x; 1.1590x over previous
//
#include <hip/hip_runtime.h>
#include <hip/hip_bf16.h>

#define Bq 2
#define Lq 384
#define Cq 128
#define Hq 8

static constexpr float WCH   = 0.11785113019775792f;  // sqrt(2/36)/2 = WC/2
static constexpr float WLc   = 0.5773502691896258f;   // sqrt(1/3)
static constexpr float LOG2E = 1.4426950408889634f;

typedef __attribute__((ext_vector_type(8))) short bf16x8;
typedef __attribute__((ext_vector_type(4))) float f32x4;

__device__ __forceinline__ unsigned short f2bf(float f) {
  __hip_bfloat16 h = __float2bfloat16(f);
  unsigned short u; __builtin_memcpy(&u, &h, 2); return u;
}
__device__ __forceinline__ unsigned packbf(float a, float b) {
  return (unsigned)f2bf(a) | ((unsigned)f2bf(b) << 16);
}
__device__ __forceinline__ float bf2f(unsigned short u) {
  unsigned x = ((unsigned)u) << 16; float f; __builtin_memcpy(&f, &x, 4); return f;
}
__device__ __forceinline__ bf16x8 ld_frag(const unsigned* p) {
  union { bf16x8 v; unsigned u[4]; } x;
  x.u[0] = p[0]; x.u[1] = p[1]; x.u[2] = p[2]; x.u[3] = p[3];
  return x.v;
}

// raw barrier: waits LDS ops only -> global prefetch loads stay in flight
#define BAR() asm volatile("s_waitcnt lgkmcnt(0)\ns_barrier" ::: "memory")

// ---------------- kernel 1a: all si projections via MFMA --------------------
// grid 144 = 12 tok-tiles(64) x 12 col-tiles(64). cols 0..383 -> q,k,v; 384..767 -> raw pts
__global__ __launch_bounds__(256) void k_proj(
    const float* __restrict__ si,
    const float* __restrict__ WQh, const float* __restrict__ WKh, const float* __restrict__ WVh,
    const float* __restrict__ WQhp, const float* __restrict__ WKhp, const float* __restrict__ WVhp,
    float* __restrict__ q, float* __restrict__ k, float* __restrict__ v,
    float* __restrict__ raw)
{
  __shared__ unsigned sm[4352*2];
  unsigned* at = sm;            // 64 rows x 68 dw (A: si, row-major bf16)
  unsigned* bt = sm + 4352;     // 64 rows x 68 dw (B: W, col-major [col][c])
  unsigned short* bt16 = (unsigned short*)bt;
  const int t = threadIdx.x;
  const int tb = blockIdx.x / 12, ct = blockIdx.x % 12;
  const int tok0 = tb*64, cg0 = ct*64;

  { // stage A: 64x128 f32 via float4
    const float4* sp = (const float4*)si;
    #pragma unroll
    for (int rep = 0; rep < 8; ++rep) {
      int idx = rep*256 + t;          // 2048 float4
      int tl = idx >> 5, cq = idx & 31;
      float4 vv = sp[(size_t)(tok0+tl)*32 + cq];
      uint2 u; u.x = packbf(vv.x, vv.y); u.y = packbf(vv.z, vv.w);
      *(uint2*)(&at[tl*68 + cq*2]) = u;
    }
  }
  { // stage B transposed: each thread owns 4 consecutive cols (cq), loops c
    const int cq = t & 15;
    const int cg = cg0 + cq*4;
    const float* Wsrc; int ncol, coff;
    if (cg < 128)      { Wsrc = WQh; ncol = 128; coff = cg; }
    else if (cg < 256) { Wsrc = WKh; ncol = 128; coff = cg-128; }
    else if (cg < 384) { Wsrc = WVh; ncol = 128; coff = cg-256; }
    else { int pc = cg-384;
      if (pc < 96)       { Wsrc = WQhp; ncol = 96;  coff = pc; }
      else if (pc < 192) { Wsrc = WKhp; ncol = 96;  coff = pc-96; }
      else               { Wsrc = WVhp; ncol = 192; coff = pc-192; } }
    #pragma unroll
    for (int rep = 0; rep < 8; ++rep) {
      int c = rep*16 + (t >> 4);
      float4 wv = *(const float4*)(Wsrc + (size_t)c*ncol + coff);
      bt16[(cq*4+0)*136 + c] = f2bf(wv.x);
      bt16[(cq*4+1)*136 + c] = f2bf(wv.y);
      bt16[(cq*4+2)*136 + c] = f2bf(wv.z);
      bt16[(cq*4+3)*136 + c] = f2bf(wv.w);
    }
  }
  __syncthreads();
  const int l = t & 63, w = t >> 6, g = l >> 4, n16 = l & 15;
  bf16x8 afr[4];
  #pragma unroll
  for (int ks = 0; ks < 4; ++ks)
    afr[ks] = ld_frag(&at[(w*16 + n16)*68 + ks*16 + g*4]);
  f32x4 acc[4];
  #pragma unroll
  for (int nl = 0; nl < 4; ++nl) { acc[nl][0]=0.f; acc[nl][1]=0.f; acc[nl][2]=0.f; acc[nl][3]=0.f; }
  #pragma unroll
  for (int nl = 0; nl < 4; ++nl)
    #pragma unroll
    for (int ks = 0; ks < 4; ++ks) {
      bf16x8 bfr = ld_frag(&bt[(nl*16 + n16)*68 + ks*16 + g*4]);
      acc[nl] = __builtin_amdgcn_mfma_f32_16x16x32_bf16(afr[ks], bfr, acc[nl], 0, 0, 0);
    }
  if (ct < 6) {
    float* dst = (ct < 2) ? q : (ct < 4) ? k : v;
    int colbase = cg0 - (ct >> 1)*128;
    #pragma unroll
    for (int nl = 0; nl < 4; ++nl)
      #pragma unroll
      for (int r = 0; r < 4; ++r)
        dst[(size_t)(tok0 + w*16 + g*4 + r)*128 + colbase + nl*16 + n16] = acc[nl][r];
  } else {
    int pcb = cg0 - 384;
    #pragma unroll
    for (int nl = 0; nl < 4; ++nl)
      #pragma unroll
      for (int r = 0; r < 4; ++r)
        raw[(size_t)(tok0 + w*16 + g*4 + r)*384 + pcb + nl*16 + n16] = acc[nl][r];
  }
}

// ---------------- kernel 1b: rigid transforms + packed GEMM operands --------
// phase1: transform points (vpt -> global); phase2: pack A/B bf16 K=32 operands
__global__ __launch_bounds__(256) void k_xform(
    const float* __restrict__ raw, const float* __restrict__ Ri, const float* __restrict__ Ti,
    const float* __restrict__ qg, const float* __restrict__ kg, const float* __restrict__ gamah,
    float* __restrict__ vpt, unsigned* __restrict__ apk, unsigned* __restrict__ bpk)
{
  __shared__ float ssq[128];
  __shared__ float spt[2][64][3];
  __shared__ float smsq[2][2][8];
  const int t = threadIdx.x;
  const int tk = t >> 7, pt = t & 127;
  const int tok = blockIdx.x*2 + tk;
  {
    const float* R = Ri + tok*9;
    const float* T = Ti + tok*3;
    int ro = (pt < 32) ? pt*3 : (pt < 64) ? 96 + (pt-32)*3 : 192 + (pt-64)*3;
    float x0 = raw[(size_t)tok*384 + ro + 0], x1 = raw[(size_t)tok*384 + ro + 1], x2 = raw[(size_t)tok*384 + ro + 2];
    float o0 = T[0] + R[0]*x0 + R[1]*x1 + R[2]*x2;
    float o1 = T[1] + R[3]*x0 + R[4]*x1 + R[5]*x2;
    float o2 = T[2] + R[6]*x0 + R[7]*x1 + R[8]*x2;
    if (pt >= 64) {
      int doff = tok*192 + (pt-64)*3;
      vpt[doff] = o0; vpt[doff+1] = o1; vpt[doff+2] = o2;
    } else {
      spt[tk][pt][0] = o0; spt[tk][pt][1] = o1; spt[tk][pt][2] = o2;
      ssq[tk*64 + pt] = o0*o0 + o1*o1 + o2*o2;
    }
  }
  __syncthreads();
  if (t < 32) {
    int tk2 = t >> 4, r = t & 15, isK = r >> 3, h = r & 7;
    int base = tk2*64 + isK*32 + h*4;
    smsq[tk2][isK][h] = ssq[base] + ssq[base+1] + ssq[base+2] + ssq[base+3];
  }
  __syncthreads();
  { // phase2: pack [tok][h][32] bf16 (16 dwords) for A (q-side) and B (k-side)
    const int ab = t >> 7, rem = t & 127;
    const int tk2 = rem >> 6, h = (rem >> 3) & 7, d0 = (t & 7)*2;
    const int tokg = blockIdx.x*2 + tk2;
    float gv = gamah[h];
    float sp = (gv > 20.f) ? gv : log1pf(__expf(gv));
    float c1 = WLc*0.25f, c2 = 2.f*WLc*sp*WCH, c3 = WLc*sp*WCH;
    unsigned* dst = (ab ? bpk : apk) + ((size_t)tokg*8 + h)*16;
    #pragma unroll
    for (int dd = 0; dd < 2; ++dd) {
      int dw = d0 + dd;
      float vv[2];
      #pragma unroll
      for (int e = 0; e < 2; ++e) {
        int kk = dw*2 + e;
        float val;
        if (kk < 16)      val = (ab ? kg : qg)[(size_t)tokg*128 + h*16 + kk] * (ab ? 1.f : c1);
        else if (kk < 28) { int pi = kk-16;
                            float cv = spt[tk2][ab*32 + h*4 + pi/3][pi%3];
                            val = ab ? cv : cv*c2; }
        else if (kk == 28) val = ab ? 1.f : -c3*smsq[tk2][0][h];
        else if (kk == 29) val = ab ? smsq[tk2][1][h] : -c3;
        else               val = 0.f;
        vv[e] = val;
      }
      dst[dw] = packbf(vv[0], vv[1]);
    }
  }
}

// ---------------- kernel geom: g[b,h,i,j] from packed operands --------------
__global__ __launch_bounds__(256) void k_geom(
    const unsigned* __restrict__ apk, const unsigned* __restrict__ bpk,
    float* __restrict__ g)
{
  __shared__ unsigned bt[384*20];
  const int t = threadIdx.x;
  const int bh = blockIdx.x / 6, ib = blockIdx.x % 6;
  const int b = bh >> 3, h = bh & 7, i0 = ib*64;
  #pragma unroll
  for (int rep = 0; rep < 6; ++rep) {
    int idx = rep*256 + t;            // 1536 uint4
    int j = idx >> 2, dq = idx & 3;
    uint4 vv = *(const uint4*)(bpk + ((size_t)(b*Lq + j)*8 + h)*16 + dq*4);
    *(uint4*)(&bt[j*20 + dq*4]) = vv;
  }
  __syncthreads();
  const int l = t & 63, w = t >> 6, g2 = l >> 4, n16 = l & 15;
  union { uint4 u; bf16x8 v; } au;
  au.u = *(const uint4*)(apk + ((size_t)(b*Lq + i0 + w*16 + n16)*8 + h)*16 + g2*4);
  bf16x8 afr = au.v;
  float* grow = g + (size_t)(b*8 + h)*Lq*Lq;
  for (int jt = 0; jt < 24; ++jt) {
    bf16x8 bfr = ld_frag(&bt[(jt*16 + n16)*20 + g2*4]);
    f32x4 acc = {0.f,0.f,0.f,0.f};
    acc = __builtin_amdgcn_mfma_f32_16x16x32_bf16(afr, bfr, acc, 0, 0, 0);
    #pragma unroll
    for (int r = 0; r < 4; ++r)
      grow[(size_t)(i0 + w*16 + g2*4 + r)*Lq + jt*16 + n16] = acc[r];
  }
}

// ---------------- kernel attn: flash-style row attention over zij -----------
// LDS dword offsets
#define ZS   0        // z row-major   64 x 68dw bf16
#define ZT   4352     // z transposed 128 x 35dw bf16
#define GS   8832     // g rows        8 x 388dw f32
#define P2O  11936    // P bf16       16 x 35dw
#define WBT  12496    // Wb^T bf16    16 x 67dw (rows 8..15 zero)
#define WMX  13568    // 4x16 f32
#define LSM  13632    // 4x16 f32
#define SCL  13696    // 8 f32
#define INV  13704    // 8 f32
#define OPTS 13712    // 192 f32
#define OS   13904    // 1024 f32
#define SMTOT 14928

__global__ __launch_bounds__(256, 2) void k_attn(
    const float* __restrict__ zij, const float* __restrict__ gmat,
    const float* __restrict__ v, const float* __restrict__ vpt,
    const float* __restrict__ Wb, const float* __restrict__ Ri, const float* __restrict__ Ti,
    float* __restrict__ feats)
{
  __shared__ unsigned sm[SMTOT];
  float* smf = (float*)sm;
  const int t = threadIdx.x;
  const int bx = blockIdx.x;
  const int b = bx / Lq, i = bx % Lq;
  const int tok = bx;
  const int l = t & 63, w = t >> 6, g = l >> 4, hh = l & 15;

  {
    const float* gp = gmat + (size_t)(b*8)*Lq*Lq + (size_t)i*Lq;
    #pragma unroll
    for (int rep = 0; rep < 3; ++rep) {
      int idx = rep*256 + t;          // 768 float4
      int h2 = idx / 96, jq = idx % 96;
      float4 gv = *(const float4*)(gp + (size_t)h2*Lq*Lq + jq*4);
      *(float4*)(&smf[GS + h2*388 + jq*4]) = gv;
    }
    unsigned short* wb16 = (unsigned short*)(sm + WBT);
    #pragma unroll
    for (int rep = 0; rep < 8; ++rep) {
      int idx = rep*256 + t;          // 16*128
      int h2 = idx >> 7, c = idx & 127;
      wb16[h2*134 + c] = (h2 < 8) ? f2bf(Wb[c*8 + h2]) : (unsigned short)0;
    }
  }
  __syncthreads();
  bf16x8 wbf[4];
  #pragma unroll
  for (int ks = 0; ks < 4; ++ks) wbf[ks] = ld_frag(&sm[WBT + hh*67 + ks*16 + g*4]);

  f32x4 opacc0 = {0.f,0.f,0.f,0.f}, opacc1 = {0.f,0.f,0.f,0.f};
  float m_run = -1e30f, l_run = 0.f;
  float va0 = 0.f, va1 = 0.f;
  int role_h = 0; const float* rp = nullptr; int rstride = 0;
  if (t < 64)       { role_h = t >> 3; rp = v   + (size_t)b*Lq*128 + role_h*16 + (t & 7)*2; rstride = 128; }
  else if (t < 160) { int qq = t - 64; role_h = qq / 12;
                      rp = vpt + (size_t)b*Lq*192 + role_h*24 + (qq % 12)*2; rstride = 192; }

  // z staging roles: thread owns (c quad c4, j-lane jr)
  const int c4 = t & 31, jr = t >> 5;
  const float4* zp = (const float4*)(zij + (size_t)tok*Lq*128);
  unsigned short* zt16 = (unsigned short*)(sm + ZT);
  float4 zr[8];
  #pragma unroll
  for (int pp = 0; pp < 8; ++pp) zr[pp] = zp[(size_t)(pp*8 + jr)*32 + c4];

  for (int ch = 0; ch < 6; ++ch) {
    const int j0 = ch*64;
    BAR();                                             // B0: prior chunk reads done
    #pragma unroll
    for (int pp = 0; pp < 8; ++pp) {
      int j = pp*8 + jr;
      uint2 u; u.x = packbf(zr[pp].x, zr[pp].y); u.y = packbf(zr[pp].z, zr[pp].w);
      *(uint2*)(&sm[ZS + j*68 + c4*2]) = u;
      zt16[(c4*4+0)*70 + j] = (unsigned short)(u.x & 0xffffu);
      zt16[(c4*4+1)*70 + j] = (unsigned short)(u.x >> 16);
      zt16[(c4*4+2)*70 + j] = (unsigned short)(u.y & 0xffffu);
      zt16[(c4*4+3)*70 + j] = (unsigned short)(u.y >> 16);
    }
    if (ch < 5) {                                      // prefetch next chunk (stays in flight)
      #pragma unroll
      for (int pp = 0; pp < 8; ++pp)
        zr[pp] = zp[(size_t)(j0 + 64 + pp*8 + jr)*32 + c4];
    }
    BAR();                                             // B1: z staged
    f32x4 bij = {0.f,0.f,0.f,0.f};
    #pragma unroll
    for (int ks = 0; ks < 4; ++ks) {
      bf16x8 a = ld_frag(&sm[ZS + (w*16 + hh)*68 + ks*16 + g*4]);
      bij = __builtin_amdgcn_mfma_f32_16x16x32_bf16(a, wbf[ks], bij, 0, 0, 0);
    }
    float s0, s1, s2, s3;
    if (hh < 8) {
      f32x4 gq = *(const f32x4*)(&smf[GS + hh*388 + j0 + w*16 + g*4]);
      s0 = gq[0] + WLc*bij[0]; s1 = gq[1] + WLc*bij[1];
      s2 = gq[2] + WLc*bij[2]; s3 = gq[3] + WLc*bij[3];
    } else { s0 = s1 = s2 = s3 = -1e30f; }
    float m4 = fmaxf(fmaxf(s0,s1), fmaxf(s2,s3));
    m4 = fmaxf(m4, __shfl_xor(m4, 16));
    m4 = fmaxf(m4, __shfl_xor(m4, 32));
    if (l < 16) smf[WMX + w*16 + l] = m4;
    BAR();                                             // B2: wave maxes ready
    float cmax = fmaxf(fmaxf(smf[WMX+hh], smf[WMX+16+hh]),
                       fmaxf(smf[WMX+32+hh], smf[WMX+48+hh]));
    float m_new = fmaxf(m_run, cmax);
    float sc = exp2f((m_run - m_new)*LOG2E);
    m_run = m_new;
    float p0 = exp2f((s0 - m_new)*LOG2E);
    float p1 = exp2f((s1 - m_new)*LOG2E);
    float p2 = exp2f((s2 - m_new)*LOG2E);
    float p3 = exp2f((s3 - m_new)*LOG2E);
    float psum = p0+p1+p2+p3;
    psum += __shfl_xor(psum, 16);
    psum += __shfl_xor(psum, 32);
    l_run = l_run*sc + psum;
    sm[P2O + hh*35 + w*8 + g*2    ] = packbf(p0, p1);
    sm[P2O + hh*35 + w*8 + g*2 + 1] = packbf(p2, p3);
    opacc0 = opacc0 * sc;
    opacc1 = opacc1 * sc;
    if (w == 0 && l < 8) smf[SCL + l] = sc;
    BAR();                                             // B3: P + scale ready
    #pragma unroll
    for (int ks = 0; ks < 2; ++ks) {
      bf16x8 bb = ld_frag(&sm[P2O + hh*35 + ks*16 + g*4]);
      bf16x8 a0 = ld_frag(&sm[ZT + ((w  )*16 + hh)*35 + ks*16 + g*4]);
      bf16x8 a1 = ld_frag(&sm[ZT + ((w+4)*16 + hh)*35 + ks*16 + g*4]);
      opacc0 = __builtin_amdgcn_mfma_f32_16x16x32_bf16(a0, bb, opacc0, 0, 0, 0);
      opacc1 = __builtin_amdgcn_mfma_f32_16x16x32_bf16(a1, bb, opacc1, 0, 0, 0);
    }
    if (t < 160) {
      float scl = smf[SCL + role_h];
      va0 *= scl; va1 *= scl;
      #pragma unroll 4
      for (int jj = 0; jj < 64; jj += 2) {
        unsigned pw = sm[P2O + role_h*35 + (jj>>1)];
        float pa = bf2f((unsigned short)(pw & 0xffffu));
        float pb = bf2f((unsigned short)(pw >> 16));
        const float* pj = rp + (size_t)(j0+jj)*rstride;
        const float* pk2 = pj + rstride;
        va0 += pa*pj[0] + pb*pk2[0];
        va1 += pa*pj[1] + pb*pk2[1];
      }
    }
  }
  __syncthreads();
  if (l < 16) smf[LSM + w*16 + l] = l_run;
  __syncthreads();
  if (t < 8) {
    float lt = smf[LSM+t] + smf[LSM+16+t] + smf[LSM+32+t] + smf[LSM+48+t];
    smf[INV + t] = 1.f / lt;
  }
  __syncthreads();
  const size_t fb = (size_t)tok * 1408;
  if (hh < 8) {
    float inv = smf[INV + hh];
    #pragma unroll
    for (int r = 0; r < 4; ++r) {
      smf[OS + hh*128 + (w  )*16 + g*4 + r] = opacc0[r]*inv;
      smf[OS + hh*128 + (w+4)*16 + g*4 + r] = opacc1[r]*inv;
    }
  }
  if (t < 64) {
    float inv = smf[INV + role_h];
    int off = role_h*16 + (t & 7)*2;
    feats[fb + 1024 + off    ] = va0*inv;
    feats[fb + 1024 + off + 1] = va1*inv;
  } else if (t < 160) {
    float inv = smf[INV + role_h];
    int qq = t - 64;
    smf[OPTS + role_h*24 + (qq%12)*2    ] = va0*inv;
    smf[OPTS + role_h*24 + (qq%12)*2 + 1] = va1*inv;
  }
  __syncthreads();
  for (int rep = 0; rep < 4; ++rep) {
    int idx = rep*256 + t;
    feats[fb + idx] = smf[OS + idx];
  }
  if (t < 64) {
    int h2 = t >> 3, p = t & 7;
    const float* R = Ri + tok*9;
    const float* T = Ti + tok*3;
    float ox = smf[OPTS + h2*24 + p*3 + 0] - T[0];
    float oy = smf[OPTS + h2*24 + p*3 + 1] - T[1];
    float oz = smf[OPTS + h2*24 + p*3 + 2] - T[2];
    float r0 = R[0]*ox + R[3]*oy + R[6]*oz;
    float r1 = R[1]*ox + R[4]*oy + R[7]*oz;
    float r2 = R[2]*ox + R[5]*oy + R[8]*oz;
    feats[fb + 1152 + (h2*8+p)*3 + 0] = r0;
    feats[fb + 1152 + (h2*8+p)*3 + 1] = r1;
    feats[fb + 1152 + (h2*8+p)*3 + 2] = r2;
    feats[fb + 1344 + h2*8 + p] = fabsf(r0) + fabsf(r1) + fabsf(r2);
  }
}

// ---------------- kernel out: feats @ WOw + WOb (fp32, split-K) -------------
__global__ __launch_bounds__(256) void k_out(
    const float* __restrict__ feats, const float* __restrict__ WOw,
    const float* __restrict__ WOb, float* __restrict__ out)
{
  __shared__ float sf[8448];
  const int t = threadIdx.x;
  const int r0 = blockIdx.x * 6;
  for (int rep = 0; rep < 33; ++rep) {
    int idx = rep*256 + t;            // 6*1408
    int row = idx / 1408, f = idx % 1408;
    sf[f*6 + row] = feats[(size_t)(r0+row)*1408 + f];
  }
  __syncthreads();
  const int c4 = t & 31, fq = t >> 5;
  float acc[6][4];
  #pragma unroll
  for (int r = 0; r < 6; ++r)
    #pragma unroll
    for (int e = 0; e < 4; ++e) acc[r][e] = 0.f;
  const float* wp = WOw + (size_t)fq*176*128 + c4*4;
  for (int f = 0; f < 176; ++f) {
    const f32x4 wv = *(const f32x4*)(wp + (size_t)f*128);
    int fg = fq*176 + f;
    float fv[6];
    #pragma unroll
    for (int r = 0; r < 6; ++r) fv[r] = sf[fg*6 + r];
    #pragma unroll
    for (int r = 0; r < 6; ++r)
      #pragma unroll
      for (int e = 0; e < 4; ++e) acc[r][e] += fv[r]*wv[e];
  }
  __syncthreads();
  #pragma unroll
  for (int r = 0; r < 6; ++r)
    #pragma unroll
    for (int e = 0; e < 4; ++e)
      sf[(fq*6 + r)*128 + c4*4 + e] = acc[r][e];
  __syncthreads();
  for (int rep = 0; rep < 3; ++rep) {
    int idx = rep*256 + t;            // 768
    int r = idx >> 7, cc = idx & 127;
    float s = 0.f;
    #pragma unroll
    for (int fq2 = 0; fq2 < 8; ++fq2) s += sf[(fq2*6 + r)*128 + cc];
    out[(size_t)(r0+r)*128 + cc] = s + WOb[cc];
  }
}

// ---------------------------------------------------------------------------
extern "C" void kernel_launch(void* const* d_in, const int* in_sizes, int n_in,
                              void* d_out, int out_size, void* d_ws, size_t ws_size,
                              hipStream_t stream) {
  const float* si    = (const float*)d_in[0];
  const float* zij   = (const float*)d_in[1];
  const float* Ri    = (const float*)d_in[2];
  const float* Ti    = (const float*)d_in[3];
  const float* WQh   = (const float*)d_in[4];
  const float* WKh   = (const float*)d_in[5];
  const float* WVh   = (const float*)d_in[6];
  const float* WQhp  = (const float*)d_in[7];
  const float* WKhp  = (const float*)d_in[8];
  const float* WVhp  = (const float*)d_in[9];
  const float* Wb    = (const float*)d_in[10];
  const float* WOw   = (const float*)d_in[11];
  const float* WOb   = (const float*)d_in[12];
  const float* gamah = (const float*)d_in[13];

  float* ws   = (float*)d_ws;
  float* q    = ws;               // 768*128
  float* k    = q    + 98304;
  float* v    = k    + 98304;
  float* vpt  = v    + 98304;     // 768*192
  float* raw  = vpt  + 147456;    // 768*384
  float* g    = raw  + 294912;    // 2*8*384*384
  float* feats= g    + 2359296;   // 768*1408
  // apk/bpk live in feats' space: written by k_xform, read by k_geom,
  // overwritten only later by k_attn (kernels are stream-ordered).
  unsigned* apk = (unsigned*)feats;          // 768*8*16 dw
  unsigned* bpk = apk + 98304;
  float* out  = (float*)d_out;

  k_proj <<<144, 256, 0, stream>>>(si, WQh, WKh, WVh, WQhp, WKhp, WVhp, q, k, v, raw);
  k_xform<<<384, 256, 0, stream>>>(raw, Ri, Ti, q, k, gamah, vpt, apk, bpk);
  k_geom <<<96,  256, 0, stream>>>(apk, bpk, g);
  k_attn <<<768, 256, 0, stream>>>(zij, g, v, vpt, Wb, Ri, Ti, feats);
  k_out  <<<128, 256, 0, stream>>>(feats, WOw, WOb, out);
}

// Round 5
// 290.520 us; speedup vs baseline: 1.2543x; 1.0823x over previous
//
#include <hip/hip_runtime.h>
#include <hip/hip_bf16.h>

#define Bq 2
#define Lq 384
#define Cq 128
#define Hq 8

static constexpr float WCH   = 0.11785113019775792f;  // sqrt(2/36)/2 = WC/2
static constexpr float WLc   = 0.5773502691896258f;   // sqrt(1/3)
static constexpr float LOG2E = 1.4426950408889634f;

typedef __fp16 f16x8 __attribute__((ext_vector_type(8)));
typedef __attribute__((ext_vector_type(4))) float f32x4;

__device__ __forceinline__ unsigned short f2h(float f) {
  __fp16 h = (__fp16)f; unsigned short u; __builtin_memcpy(&u, &h, 2); return u;
}
__device__ __forceinline__ unsigned packh(float a, float b) {
  auto v = __builtin_amdgcn_cvt_pkrtz(a, b);
  unsigned u; __builtin_memcpy(&u, &v, 4); return u;
}
__device__ __forceinline__ f16x8 ld_frag16(const unsigned* p) {
  union { f16x8 v; unsigned u[4]; } x;
  x.u[0] = p[0]; x.u[1] = p[1]; x.u[2] = p[2]; x.u[3] = p[3];
  return x.v;
}

// raw barrier: waits LDS ops only -> global prefetch loads stay in flight
#define BAR() asm volatile("s_waitcnt lgkmcnt(0)\ns_barrier" ::: "memory")

// ---------------- kernel 1a: all si projections via MFMA --------------------
// grid 144 = 12 tok-tiles(64) x 12 col-tiles(64). cols 0..255 -> q,k (f32);
// 256..383 -> v (fp16, transposed to vt_g); 384..767 -> raw pts (f32)
__global__ __launch_bounds__(256) void k_proj(
    const float* __restrict__ si,
    const float* __restrict__ WQh, const float* __restrict__ WKh, const float* __restrict__ WVh,
    const float* __restrict__ WQhp, const float* __restrict__ WKhp, const float* __restrict__ WVhp,
    float* __restrict__ q, float* __restrict__ k, unsigned short* __restrict__ vt_g,
    float* __restrict__ raw)
{
  __shared__ unsigned sm[4352*2];
  unsigned* at = sm;            // 64 rows x 68 dw (A: si, row-major f16)
  unsigned* bt = sm + 4352;     // 64 rows x 68 dw (B: W, col-major [col][c] f16)
  unsigned short* bt16 = (unsigned short*)bt;
  const int t = threadIdx.x;
  const int tb = blockIdx.x / 12, ct = blockIdx.x % 12;
  const int tok0 = tb*64, cg0 = ct*64;

  { // stage A: 64x128 f32 via float4
    const float4* sp = (const float4*)si;
    #pragma unroll
    for (int rep = 0; rep < 8; ++rep) {
      int idx = rep*256 + t;          // 2048 float4
      int tl = idx >> 5, cq = idx & 31;
      float4 vv = sp[(size_t)(tok0+tl)*32 + cq];
      uint2 u; u.x = packh(vv.x, vv.y); u.y = packh(vv.z, vv.w);
      *(uint2*)(&at[tl*68 + cq*2]) = u;
    }
  }
  { // stage B transposed: each thread owns 4 consecutive cols (cq), loops c
    const int cq = t & 15;
    const int cg = cg0 + cq*4;
    const float* Wsrc; int ncol, coff;
    if (cg < 128)      { Wsrc = WQh; ncol = 128; coff = cg; }
    else if (cg < 256) { Wsrc = WKh; ncol = 128; coff = cg-128; }
    else if (cg < 384) { Wsrc = WVh; ncol = 128; coff = cg-256; }
    else { int pc = cg-384;
      if (pc < 96)       { Wsrc = WQhp; ncol = 96;  coff = pc; }
      else if (pc < 192) { Wsrc = WKhp; ncol = 96;  coff = pc-96; }
      else               { Wsrc = WVhp; ncol = 192; coff = pc-192; } }
    #pragma unroll
    for (int rep = 0; rep < 8; ++rep) {
      int c = rep*16 + (t >> 4);
      float4 wv = *(const float4*)(Wsrc + (size_t)c*ncol + coff);
      bt16[(cq*4+0)*136 + c] = f2h(wv.x);
      bt16[(cq*4+1)*136 + c] = f2h(wv.y);
      bt16[(cq*4+2)*136 + c] = f2h(wv.z);
      bt16[(cq*4+3)*136 + c] = f2h(wv.w);
    }
  }
  __syncthreads();
  const int l = t & 63, w = t >> 6, g = l >> 4, n16 = l & 15;
  f16x8 afr[4];
  #pragma unroll
  for (int ks = 0; ks < 4; ++ks)
    afr[ks] = ld_frag16(&at[(w*16 + n16)*68 + ks*16 + g*4]);
  f32x4 acc[4];
  #pragma unroll
  for (int nl = 0; nl < 4; ++nl) { acc[nl][0]=0.f; acc[nl][1]=0.f; acc[nl][2]=0.f; acc[nl][3]=0.f; }
  #pragma unroll
  for (int nl = 0; nl < 4; ++nl)
    #pragma unroll
    for (int ks = 0; ks < 4; ++ks) {
      f16x8 bfr = ld_frag16(&bt[(nl*16 + n16)*68 + ks*16 + g*4]);
      acc[nl] = __builtin_amdgcn_mfma_f32_16x16x32_f16(afr[ks], bfr, acc[nl], 0, 0, 0);
    }
  if (ct < 4) {
    float* dst = (ct < 2) ? q : k;
    int colbase = cg0 - (ct >> 1)*128;
    #pragma unroll
    for (int nl = 0; nl < 4; ++nl)
      #pragma unroll
      for (int r = 0; r < 4; ++r)
        dst[(size_t)(tok0 + w*16 + g*4 + r)*128 + colbase + nl*16 + n16] = acc[nl][r];
  } else if (ct < 6) {
    int colbase = cg0 - 256;          // v cols, store transposed fp16
    #pragma unroll
    for (int nl = 0; nl < 4; ++nl)
      #pragma unroll
      for (int r = 0; r < 4; ++r)
        vt_g[(size_t)(colbase + nl*16 + n16)*768 + tok0 + w*16 + g*4 + r] = f2h(acc[nl][r]);
  } else {
    int pcb = cg0 - 384;
    #pragma unroll
    for (int nl = 0; nl < 4; ++nl)
      #pragma unroll
      for (int r = 0; r < 4; ++r)
        raw[(size_t)(tok0 + w*16 + g*4 + r)*384 + pcb + nl*16 + n16] = acc[nl][r];
  }
}

// ---------------- kernel 1b: rigid transforms + packed GEMM operands --------
// phase1: transform points (vpt^T fp16 -> global); phase2: pack A/B f16 K=32 operands
__global__ __launch_bounds__(256) void k_xform(
    const float* __restrict__ raw, const float* __restrict__ Ri, const float* __restrict__ Ti,
    const float* __restrict__ qg, const float* __restrict__ kg, const float* __restrict__ gamah,
    unsigned short* __restrict__ vptt, unsigned* __restrict__ apk, unsigned* __restrict__ bpk)
{
  __shared__ float ssq[128];
  __shared__ float spt[2][64][3];
  __shared__ float smsq[2][2][8];
  const int t = threadIdx.x;
  const int tk = t >> 7, pt = t & 127;
  const int tok = blockIdx.x*2 + tk;
  {
    const float* R = Ri + tok*9;
    const float* T = Ti + tok*3;
    int ro = (pt < 32) ? pt*3 : (pt < 64) ? 96 + (pt-32)*3 : 192 + (pt-64)*3;
    float x0 = raw[(size_t)tok*384 + ro + 0], x1 = raw[(size_t)tok*384 + ro + 1], x2 = raw[(size_t)tok*384 + ro + 2];
    float o0 = T[0] + R[0]*x0 + R[1]*x1 + R[2]*x2;
    float o1 = T[1] + R[3]*x0 + R[4]*x1 + R[5]*x2;
    float o2 = T[2] + R[6]*x0 + R[7]*x1 + R[8]*x2;
    if (pt >= 64) {
      int col = (pt-64)*3;
      vptt[(size_t)(col+0)*768 + tok] = f2h(o0);
      vptt[(size_t)(col+1)*768 + tok] = f2h(o1);
      vptt[(size_t)(col+2)*768 + tok] = f2h(o2);
    } else {
      spt[tk][pt][0] = o0; spt[tk][pt][1] = o1; spt[tk][pt][2] = o2;
      ssq[tk*64 + pt] = o0*o0 + o1*o1 + o2*o2;
    }
  }
  __syncthreads();
  if (t < 32) {
    int tk2 = t >> 4, r = t & 15, isK = r >> 3, h = r & 7;
    int base = tk2*64 + isK*32 + h*4;
    smsq[tk2][isK][h] = ssq[base] + ssq[base+1] + ssq[base+2] + ssq[base+3];
  }
  __syncthreads();
  { // phase2: pack [tok][h][32] f16 (16 dwords) for A (q-side) and B (k-side)
    const int ab = t >> 7, rem = t & 127;
    const int tk2 = rem >> 6, h = (rem >> 3) & 7, d0 = (t & 7)*2;
    const int tokg = blockIdx.x*2 + tk2;
    float gv = gamah[h];
    float sp = (gv > 20.f) ? gv : log1pf(__expf(gv));
    float c1 = WLc*0.25f, c2 = 2.f*WLc*sp*WCH, c3 = WLc*sp*WCH;
    unsigned* dst = (ab ? bpk : apk) + ((size_t)tokg*8 + h)*16;
    #pragma unroll
    for (int dd = 0; dd < 2; ++dd) {
      int dw = d0 + dd;
      float vv[2];
      #pragma unroll
      for (int e = 0; e < 2; ++e) {
        int kk = dw*2 + e;
        float val;
        if (kk < 16)      val = (ab ? kg : qg)[(size_t)tokg*128 + h*16 + kk] * (ab ? 1.f : c1);
        else if (kk < 28) { int pi = kk-16;
                            float cv = spt[tk2][ab*32 + h*4 + pi/3][pi%3];
                            val = ab ? cv : cv*c2; }
        else if (kk == 28) val = ab ? 1.f : -c3*smsq[tk2][0][h];
        else if (kk == 29) val = ab ? smsq[tk2][1][h] : -c3;
        else               val = 0.f;
        vv[e] = val;
      }
      dst[dw] = packh(vv[0], vv[1]);
    }
  }
}

// ---------------- kernel geom: g[b,h,i,j] from packed operands --------------
__global__ __launch_bounds__(256) void k_geom(
    const unsigned* __restrict__ apk, const unsigned* __restrict__ bpk,
    float* __restrict__ g)
{
  __shared__ unsigned bt[384*20];
  const int t = threadIdx.x;
  const int bh = blockIdx.x / 6, ib = blockIdx.x % 6;
  const int b = bh >> 3, h = bh & 7, i0 = ib*64;
  #pragma unroll
  for (int rep = 0; rep < 6; ++rep) {
    int idx = rep*256 + t;            // 1536 uint4
    int j = idx >> 2, dq = idx & 3;
    uint4 vv = *(const uint4*)(bpk + ((size_t)(b*Lq + j)*8 + h)*16 + dq*4);
    *(uint4*)(&bt[j*20 + dq*4]) = vv;
  }
  __syncthreads();
  const int l = t & 63, w = t >> 6, g2 = l >> 4, n16 = l & 15;
  union { uint4 u; f16x8 v; } au;
  au.u = *(const uint4*)(apk + ((size_t)(b*Lq + i0 + w*16 + n16)*8 + h)*16 + g2*4);
  f16x8 afr = au.v;
  float* grow = g + (size_t)(b*8 + h)*Lq*Lq;
  for (int jt = 0; jt < 24; ++jt) {
    f16x8 bfr = ld_frag16(&bt[(jt*16 + n16)*20 + g2*4]);
    f32x4 acc = {0.f,0.f,0.f,0.f};
    acc = __builtin_amdgcn_mfma_f32_16x16x32_f16(afr, bfr, acc, 0, 0, 0);
    #pragma unroll
    for (int r = 0; r < 4; ++r)
      grow[(size_t)(i0 + w*16 + g2*4 + r)*Lq + jt*16 + n16] = acc[r];
  }
}

// ---------------- kernel attn: flash-style row attention over zij -----------
// LDS dword offsets (total 20440 dw = 81760 B -> 2 blocks/CU)
#define ZSo   0        // z row-major  64 x 66 dw f16   [aliased as OPTS post-loop]
#define ZTo   4224     // z^T         128 x 35 dw f16
#define VTo   8704     // v^T         128 x 33 dw f16   [aliased as OS post-loop]
#define VPo   12928    // vpt^T       192 x 33 dw f16
#define P2o   19264    // P f16        16 x 35 dw
#define WBo   19824    // Wb^T f16      8 x 68 dw
#define WMo   20368    // 64 f32 wave maxes  [aliased as LSM post-loop]
#define INVo  20432    // 8 f32
#define SMTOT 20440
#define OPo   0        // alias ZSo: OPTS 192 f32
#define OSo   8704     // alias VTo: o_pair 1024 f32

__global__ __launch_bounds__(256, 2) void k_attn(
    const float* __restrict__ zij, const float* __restrict__ gmat,
    const unsigned short* __restrict__ vt_g, const unsigned short* __restrict__ vptt,
    const float* __restrict__ Wb, const float* __restrict__ Ri, const float* __restrict__ Ti,
    float* __restrict__ feats)
{
  __shared__ unsigned sm[SMTOT];
  float* smf = (float*)sm;
  unsigned short* zt16 = (unsigned short*)(sm + ZTo);
  const int t = threadIdx.x;
  const int bx = blockIdx.x;
  const int b = bx / Lq, i = bx % Lq;
  const int l = t & 63, w = t >> 6, g = l >> 4, hh = l & 15;

  // ---- chunk-0 prefetch (stays in flight across init) ----
  const int c4 = t & 31, jr = t >> 5;
  const float4* zp = (const float4*)(zij + (size_t)bx*Lq*128);
  float4 zr[8];
  #pragma unroll
  for (int pp = 0; pp < 8; ++pp) zr[pp] = zp[(size_t)(pp*8 + jr)*32 + c4];
  const uint4* vtp = (const uint4*)vt_g;     // [col][768/8]: col*96 + b*48 + ch*8 + seg
  const uint4* vpp = (const uint4*)vptt;
  uint4 vtr[4], vpr[6];
  #pragma unroll
  for (int q2 = 0; q2 < 4; ++q2) {
    int u = q2*256 + t, row = u >> 3, seg = u & 7;
    vtr[q2] = vtp[row*96 + b*48 + seg];
  }
  #pragma unroll
  for (int q2 = 0; q2 < 6; ++q2) {
    int u = q2*256 + t, row = u >> 3, seg = u & 7;
    vpr[q2] = vpp[row*96 + b*48 + seg];
  }

  // ---- g rows -> registers (only hh<8 lanes use them) ----
  f32x4 greg[6];
  #pragma unroll
  for (int ch = 0; ch < 6; ++ch) { greg[ch][0]=0.f; greg[ch][1]=0.f; greg[ch][2]=0.f; greg[ch][3]=0.f; }
  if (hh < 8) {
    const float* gp = gmat + ((size_t)(b*8 + hh)*Lq + i)*Lq;
    #pragma unroll
    for (int ch = 0; ch < 6; ++ch)
      greg[ch] = *(const f32x4*)(gp + ch*64 + w*16 + g*4);
  }

  { // ---- Wb^T staging: 8 rows x 128 c, f16 ----
    unsigned short* wb16 = (unsigned short*)(sm + WBo);
    #pragma unroll
    for (int rep = 0; rep < 4; ++rep) {
      int idx = rep*256 + t;          // 1024
      int c = idx >> 3, h2 = idx & 7;
      wb16[h2*136 + c] = f2h(Wb[c*8 + h2]);
    }
  }
  __syncthreads();
  const f16x8 zf8 = {0,0,0,0,0,0,0,0};
  f16x8 wbf[4];
  #pragma unroll
  for (int ks = 0; ks < 4; ++ks)
    wbf[ks] = (hh < 8) ? ld_frag16(&sm[WBo + hh*68 + ks*16 + g*4]) : zf8;

  f32x4 opacc0 = {0.f,0.f,0.f,0.f}, opacc1 = {0.f,0.f,0.f,0.f};
  f32x4 anv0 = {0.f,0.f,0.f,0.f}, anv1 = {0.f,0.f,0.f,0.f};
  f32x4 apv0 = {0.f,0.f,0.f,0.f}, apv1 = {0.f,0.f,0.f,0.f}, apv2 = {0.f,0.f,0.f,0.f};
  float m_run = -1e30f, l_run = 0.f;
  float mr0 = -1e30f, mr1 = -1e30f, mr2 = -1e30f, mr3 = -1e30f;

  for (int ch = 0; ch < 6; ++ch) {
    BAR();                                             // B0: prior LDS reads done
    #pragma unroll
    for (int pp = 0; pp < 8; ++pp) {
      int j = pp*8 + jr;
      unsigned u0 = packh(zr[pp].x, zr[pp].y), u1 = packh(zr[pp].z, zr[pp].w);
      uint2 u; u.x = u0; u.y = u1;
      *(uint2*)(&sm[ZSo + j*66 + c4*2]) = u;
      zt16[(c4*4+0)*70 + j] = (unsigned short)(u0 & 0xffffu);
      zt16[(c4*4+1)*70 + j] = (unsigned short)(u0 >> 16);
      zt16[(c4*4+2)*70 + j] = (unsigned short)(u1 & 0xffffu);
      zt16[(c4*4+3)*70 + j] = (unsigned short)(u1 >> 16);
    }
    #pragma unroll
    for (int q2 = 0; q2 < 4; ++q2) {
      int u = q2*256 + t, row = u >> 3, seg = u & 7;
      sm[VTo + row*33 + seg*4    ] = vtr[q2].x;
      sm[VTo + row*33 + seg*4 + 1] = vtr[q2].y;
      sm[VTo + row*33 + seg*4 + 2] = vtr[q2].z;
      sm[VTo + row*33 + seg*4 + 3] = vtr[q2].w;
    }
    #pragma unroll
    for (int q2 = 0; q2 < 6; ++q2) {
      int u = q2*256 + t, row = u >> 3, seg = u & 7;
      sm[VPo + row*33 + seg*4    ] = vpr[q2].x;
      sm[VPo + row*33 + seg*4 + 1] = vpr[q2].y;
      sm[VPo + row*33 + seg*4 + 2] = vpr[q2].z;
      sm[VPo + row*33 + seg*4 + 3] = vpr[q2].w;
    }
    if (ch < 5) {                                      // prefetch next chunk
      int j0n = (ch+1)*64;
      #pragma unroll
      for (int pp = 0; pp < 8; ++pp)
        zr[pp] = zp[(size_t)(j0n + pp*8 + jr)*32 + c4];
      #pragma unroll
      for (int q2 = 0; q2 < 4; ++q2) {
        int u = q2*256 + t, row = u >> 3, seg = u & 7;
        vtr[q2] = vtp[row*96 + b*48 + (ch+1)*8 + seg];
      }
      #pragma unroll
      for (int q2 = 0; q2 < 6; ++q2) {
        int u = q2*256 + t, row = u >> 3, seg = u & 7;
        vpr[q2] = vpp[row*96 + b*48 + (ch+1)*8 + seg];
      }
    }
    BAR();                                             // B1: staged
    f32x4 bij = {0.f,0.f,0.f,0.f};
    #pragma unroll
    for (int ks = 0; ks < 4; ++ks) {
      f16x8 a = ld_frag16(&sm[ZSo + (w*16 + hh)*66 + ks*16 + g*4]);
      bij = __builtin_amdgcn_mfma_f32_16x16x32_f16(a, wbf[ks], bij, 0, 0, 0);
    }
    float s0, s1, s2, s3;
    if (hh < 8) {
      s0 = greg[ch][0] + WLc*bij[0]; s1 = greg[ch][1] + WLc*bij[1];
      s2 = greg[ch][2] + WLc*bij[2]; s3 = greg[ch][3] + WLc*bij[3];
    } else { s0 = s1 = s2 = s3 = -1e30f; }
    float m4 = fmaxf(fmaxf(s0,s1), fmaxf(s2,s3));
    m4 = fmaxf(m4, __shfl_xor(m4, 16));
    m4 = fmaxf(m4, __shfl_xor(m4, 32));
    if (l < 16) smf[WMo + w*16 + l] = m4;
    BAR();                                             // B2: wave maxes ready
    // per-lane (head hh) softmax update
    float cmax = fmaxf(fmaxf(smf[WMo+hh], smf[WMo+16+hh]),
                       fmaxf(smf[WMo+32+hh], smf[WMo+48+hh]));
    float m_new = fmaxf(m_run, cmax);
    float sc = exp2f((m_run - m_new)*LOG2E);
    m_run = m_new;
    float p0 = exp2f((s0 - m_new)*LOG2E);
    float p1 = exp2f((s1 - m_new)*LOG2E);
    float p2 = exp2f((s2 - m_new)*LOG2E);
    float p3 = exp2f((s3 - m_new)*LOG2E);
    float psum = p0+p1+p2+p3;
    psum += __shfl_xor(psum, 16);
    psum += __shfl_xor(psum, 32);
    l_run = l_run*sc + psum;
    sm[P2o + hh*35 + w*8 + g*2    ] = packh(p0, p1);
    sm[P2o + hh*35 + w*8 + g*2 + 1] = packh(p2, p3);
    // per-row (head g*4+r) scales for the A=P MFMAs
    float scr0, scr1, scr2, scr3;
    {
      int hr = g*4;
      float cm, mn;
      cm = fmaxf(fmaxf(smf[WMo+hr], smf[WMo+16+hr]), fmaxf(smf[WMo+32+hr], smf[WMo+48+hr]));
      mn = fmaxf(mr0, cm); scr0 = exp2f((mr0 - mn)*LOG2E); mr0 = mn;
      cm = fmaxf(fmaxf(smf[WMo+hr+1], smf[WMo+17+hr]), fmaxf(smf[WMo+33+hr], smf[WMo+49+hr]));
      mn = fmaxf(mr1, cm); scr1 = exp2f((mr1 - mn)*LOG2E); mr1 = mn;
      cm = fmaxf(fmaxf(smf[WMo+hr+2], smf[WMo+18+hr]), fmaxf(smf[WMo+34+hr], smf[WMo+50+hr]));
      mn = fmaxf(mr2, cm); scr2 = exp2f((mr2 - mn)*LOG2E); mr2 = mn;
      cm = fmaxf(fmaxf(smf[WMo+hr+3], smf[WMo+19+hr]), fmaxf(smf[WMo+35+hr], smf[WMo+51+hr]));
      mn = fmaxf(mr3, cm); scr3 = exp2f((mr3 - mn)*LOG2E); mr3 = mn;
    }
    opacc0 = opacc0 * sc;
    opacc1 = opacc1 * sc;
    anv0[0]*=scr0; anv0[1]*=scr1; anv0[2]*=scr2; anv0[3]*=scr3;
    anv1[0]*=scr0; anv1[1]*=scr1; anv1[2]*=scr2; anv1[3]*=scr3;
    apv0[0]*=scr0; apv0[1]*=scr1; apv0[2]*=scr2; apv0[3]*=scr3;
    apv1[0]*=scr0; apv1[1]*=scr1; apv1[2]*=scr2; apv1[3]*=scr3;
    apv2[0]*=scr0; apv2[1]*=scr1; apv2[2]*=scr2; apv2[3]*=scr3;
    BAR();                                             // B3: P ready
    #pragma unroll
    for (int ks = 0; ks < 2; ++ks) {
      f16x8 bb = ld_frag16(&sm[P2o + hh*35 + ks*16 + g*4]);
      f16x8 a0 = ld_frag16(&sm[ZTo + ((w  )*16 + hh)*35 + ks*16 + g*4]);
      f16x8 a1 = ld_frag16(&sm[ZTo + ((w+4)*16 + hh)*35 + ks*16 + g*4]);
      opacc0 = __builtin_amdgcn_mfma_f32_16x16x32_f16(a0, bb, opacc0, 0, 0, 0);
      opacc1 = __builtin_amdgcn_mfma_f32_16x16x32_f16(a1, bb, opacc1, 0, 0, 0);
      f16x8 v0 = ld_frag16(&sm[VTo + ((2*w  )*16 + hh)*33 + ks*16 + g*4]);
      f16x8 v1 = ld_frag16(&sm[VTo + ((2*w+1)*16 + hh)*33 + ks*16 + g*4]);
      anv0 = __builtin_amdgcn_mfma_f32_16x16x32_f16(bb, v0, anv0, 0, 0, 0);
      anv1 = __builtin_amdgcn_mfma_f32_16x16x32_f16(bb, v1, anv1, 0, 0, 0);
      f16x8 p0f = ld_frag16(&sm[VPo + ((3*w  )*16 + hh)*33 + ks*16 + g*4]);
      f16x8 p1f = ld_frag16(&sm[VPo + ((3*w+1)*16 + hh)*33 + ks*16 + g*4]);
      f16x8 p2f = ld_frag16(&sm[VPo + ((3*w+2)*16 + hh)*33 + ks*16 + g*4]);
      apv0 = __builtin_amdgcn_mfma_f32_16x16x32_f16(bb, p0f, apv0, 0, 0, 0);
      apv1 = __builtin_amdgcn_mfma_f32_16x16x32_f16(bb, p1f, apv1, 0, 0, 0);
      apv2 = __builtin_amdgcn_mfma_f32_16x16x32_f16(bb, p2f, apv2, 0, 0, 0);
    }
  }
  __syncthreads();
  if (l < 16) smf[WMo + w*16 + l] = l_run;             // LSM alias
  __syncthreads();
  if (t < 8) {
    float lt = smf[WMo+t] + smf[WMo+16+t] + smf[WMo+32+t] + smf[WMo+48+t];
    smf[INVo + t] = 1.f / lt;
  }
  __syncthreads();
  const size_t fb = (size_t)bx * 1408;
  if (hh < 8) {                                        // o_pair -> OS (alias VT)
    float inv = smf[INVo + hh];
    #pragma unroll
    for (int r = 0; r < 4; ++r) {
      smf[OSo + hh*128 + (w  )*16 + g*4 + r] = opacc0[r]*inv;
      smf[OSo + hh*128 + (w+4)*16 + g*4 + r] = opacc1[r]*inv;
    }
  }
  // o_val diagonal extraction -> feats[1024..1151]
  {
    int nt0 = 2*w;
    if (g == (nt0 >> 2))
      feats[fb + 1024 + nt0*16 + hh] = anv0[nt0 & 3] * smf[INVo + nt0];
    int nt1 = 2*w + 1;
    if (g == (nt1 >> 2))
      feats[fb + 1024 + nt1*16 + hh] = anv1[nt1 & 3] * smf[INVo + nt1];
  }
  // opt diagonal extraction -> OPTS (alias ZS)
  #pragma unroll
  for (int ti = 0; ti < 3; ++ti) {
    int col = (3*w + ti)*16 + hh;
    int h2 = col / 24;
    float val = 0.f;
    #pragma unroll
    for (int r = 0; r < 4; ++r) {
      float av = (ti == 0) ? apv0[r] : (ti == 1) ? apv1[r] : apv2[r];
      if (h2 == g*4 + r) val = av;
    }
    if (h2 >= g*4 && h2 < g*4 + 4)
      smf[OPo + col] = val * smf[INVo + h2];
  }
  __syncthreads();
  #pragma unroll
  for (int rep = 0; rep < 4; ++rep) {
    int idx = rep*256 + t;
    feats[fb + idx] = smf[OSo + idx];
  }
  if (t < 64) {
    int h2 = t >> 3, p = t & 7;
    const float* R = Ri + bx*9;
    const float* T = Ti + bx*3;
    float ox = smf[OPo + h2*24 + p*3 + 0] - T[0];
    float oy = smf[OPo + h2*24 + p*3 + 1] - T[1];
    float oz = smf[OPo + h2*24 + p*3 + 2] - T[2];
    float r0 = R[0]*ox + R[3]*oy + R[6]*oz;
    float r1 = R[1]*ox + R[4]*oy + R[7]*oz;
    float r2 = R[2]*ox + R[5]*oy + R[8]*oz;
    feats[fb + 1152 + (h2*8+p)*3 + 0] = r0;
    feats[fb + 1152 + (h2*8+p)*3 + 1] = r1;
    feats[fb + 1152 + (h2*8+p)*3 + 2] = r2;
    feats[fb + 1344 + h2*8 + p] = fabsf(r0) + fabsf(r1) + fabsf(r2);
  }
}

// ---------------- kernel out: feats @ WOw + WOb (fp32, split-K) -------------
__global__ __launch_bounds__(256) void k_out(
    const float* __restrict__ feats, const float* __restrict__ WOw,
    const float* __restrict__ WOb, float* __restrict__ out)
{
  __shared__ float sf[8448];
  const int t = threadIdx.x;
  const int r0 = blockIdx.x * 6;
  for (int rep = 0; rep < 33; ++rep) {
    int idx = rep*256 + t;            // 6*1408
    int row = idx / 1408, f = idx % 1408;
    sf[f*6 + row] = feats[(size_t)(r0+row)*1408 + f];
  }
  __syncthreads();
  const int c4 = t & 31, fq = t >> 5;
  float acc[6][4];
  #pragma unroll
  for (int r = 0; r < 6; ++r)
    #pragma unroll
    for (int e = 0; e < 4; ++e) acc[r][e] = 0.f;
  const float* wp = WOw + (size_t)fq*176*128 + c4*4;
  for (int f = 0; f < 176; ++f) {
    const f32x4 wv = *(const f32x4*)(wp + (size_t)f*128);
    int fg = fq*176 + f;
    float fv[6];
    #pragma unroll
    for (int r = 0; r < 6; ++r) fv[r] = sf[fg*6 + r];
    #pragma unroll
    for (int r = 0; r < 6; ++r)
      #pragma unroll
      for (int e = 0; e < 4; ++e) acc[r][e] += fv[r]*wv[e];
  }
  __syncthreads();
  #pragma unroll
  for (int r = 0; r < 6; ++r)
    #pragma unroll
    for (int e = 0; e < 4; ++e)
      sf[(fq*6 + r)*128 + c4*4 + e] = acc[r][e];
  __syncthreads();
  for (int rep = 0; rep < 3; ++rep) {
    int idx = rep*256 + t;            // 768
    int r = idx >> 7, cc = idx & 127;
    float s = 0.f;
    #pragma unroll
    for (int fq2 = 0; fq2 < 8; ++fq2) s += sf[(fq2*6 + r)*128 + cc];
    out[(size_t)(r0+r)*128 + cc] = s + WOb[cc];
  }
}

// ---------------------------------------------------------------------------
extern "C" void kernel_launch(void* const* d_in, const int* in_sizes, int n_in,
                              void* d_out, int out_size, void* d_ws, size_t ws_size,
                              hipStream_t stream) {
  const float* si    = (const float*)d_in[0];
  const float* zij   = (const float*)d_in[1];
  const float* Ri    = (const float*)d_in[2];
  const float* Ti    = (const float*)d_in[3];
  const float* WQh   = (const float*)d_in[4];
  const float* WKh   = (const float*)d_in[5];
  const float* WVh   = (const float*)d_in[6];
  const float* WQhp  = (const float*)d_in[7];
  const float* WKhp  = (const float*)d_in[8];
  const float* WVhp  = (const float*)d_in[9];
  const float* Wb    = (const float*)d_in[10];
  const float* WOw   = (const float*)d_in[11];
  const float* WOb   = (const float*)d_in[12];
  const float* gamah = (const float*)d_in[13];

  float* ws   = (float*)d_ws;
  float* q    = ws;                         // 98304 f32
  float* k    = q + 98304;                  // 98304
  float* raw  = k + 98304;                  // 294912
  float* g    = raw + 294912;               // 2359296
  float* feats= g + 2359296;                // 1081344
  unsigned short* vt_g = (unsigned short*)(feats + 1081344);  // 98304 f16
  unsigned short* vptt = vt_g + 98304;                        // 147456 f16
  // apk/bpk live in feats' space: written by k_xform, read by k_geom,
  // overwritten only later by k_attn (kernels are stream-ordered).
  unsigned* apk = (unsigned*)feats;         // 768*8*16 dw
  unsigned* bpk = apk + 98304;
  float* out  = (float*)d_out;

  k_proj <<<144, 256, 0, stream>>>(si, WQh, WKh, WVh, WQhp, WKhp, WVhp, q, k, vt_g, raw);
  k_xform<<<384, 256, 0, stream>>>(raw, Ri, Ti, q, k, gamah, vptt, apk, bpk);
  k_geom <<<96,  256, 0, stream>>>(apk, bpk, g);
  k_attn <<<768, 256, 0, stream>>>(zij, g, vt_g, vptt, Wb, Ri, Ti, feats);
  k_out  <<<128, 256, 0, stream>>>(feats, WOw, WOb, out);
}